// Round 20
// baseline (250.629 us; speedup 1.0000x reference)
//
#include <hip/hip_runtime.h>

#define Nn 50000
#define Ee 600000
#define Gg 8
#define Dd 128
#define NP 50048
#define NCHUNK 49           // scan blocks (1024 nodes each)

#define HWORDS 25024        // ceil(N/2); 2x16-bit counters per word
#define HB 16
#define HIST_BLOCKS (2 * HB)          // 32
#define W12_BLOCKS 16
#define W123_BLOCKS 64
#define DTILE 64
#define DPBLK ((Nn + DTILE - 1) / DTILE)   // 782
#define RA_BLOCKS 128
#define RA_CHUNK ((DPBLK + RA_BLOCKS - 1) / RA_BLOCKS)  // 7

// ---------------- hist + piggyback W12/e1/e2 + zero accumulators/flags ----
__global__ __launch_bounds__(1024) void hist_kernel(
    const int* __restrict__ src, const int* __restrict__ dst,
    unsigned int* __restrict__ phist,
    const float* __restrict__ W1, const float* __restrict__ W2,
    const float* __restrict__ W3, const float* __restrict__ b1,
    const float* __restrict__ b2,
    float* __restrict__ W12, float* __restrict__ e1, float* __restrict__ e2,
    int* __restrict__ accz)   // pw1(8),pw2(8),cnt(8),fs(64) -> 88 words
{
    __shared__ unsigned int h[HWORDS];
    int t = threadIdx.x;
    int b = blockIdx.x;

    if (b < HIST_BLOCKS) {
        for (int i = t; i < HWORDS; i += 1024) h[i] = 0u;
        __syncthreads();
        int part = b >> 1;
        const int* arr = (b & 1) ? dst : src;
        int e0 = part * (Ee / HB);
        int eN = e0 + (Ee / HB);
        for (int e = e0 + t; e < eN; e += 1024) {
            int n = arr[e];
            atomicAdd(&h[n >> 1], 1u << ((n & 1) << 4));
        }
        __syncthreads();
        unsigned int* out = phist + (size_t)b * HWORDS;
        for (int i = t; i < HWORDS; i += 1024) out[i] = h[i];
    } else if (b < HIST_BLOCKS + W12_BLOCKS) {
        int j = (b - HIST_BLOCKS) * 8 + (t & 7);
        int k = t >> 3;
        float a = 0.f;
#pragma unroll 8
        for (int m = 0; m < 128; ++m) a += W1[k * 128 + m] * W2[m * 128 + j];
        W12[k * 128 + j] = a;
    } else {
        if (t < 128) {
            float a = 0.f;
#pragma unroll 8
            for (int k = 0; k < 128; ++k) a += b1[k] * W2[k * 128 + t];
            e1[t] = a;
        } else if (t < 256) {
            int c = t - 128;
            float a = 0.f;
#pragma unroll 8
            for (int k = 0; k < 128; ++k) a += b2[k] * W3[k * 128 + c];
            e2[c] = a;
        } else if (t < 256 + 88) {
            accz[t - 256] = 0;      // zero pw1, pw2, cnt, lookback flags
        }
    }
}

// ---------------- fused: partial-reduce + norms + z + lookback scan --------
__global__ __launch_bounds__(256) void scan_fused(
    const unsigned int* __restrict__ phist, const int* __restrict__ gid,
    float* __restrict__ srcn, float* __restrict__ pq, float* __restrict__ z,
    int* __restrict__ cnt, int* __restrict__ row_ptr,
    int* __restrict__ fs,
    const float* __restrict__ W12, const float* __restrict__ W3,
    const float* __restrict__ e1,
    float* __restrict__ W123, float* __restrict__ e1b)
{
    int b = blockIdx.x, t = threadIdx.x;
    if (b < NCHUNK) {
        __shared__ int tsum[256];
        __shared__ int lc[Gg];
        __shared__ int pre[64];
        __shared__ int sbase;
        if (t < Gg) lc[t] = 0;
        __syncthreads();

        int d4[4];
        int wbase = b * 512 + t * 2;
#pragma unroll
        for (int wi = 0; wi < 2; ++wi) {
            int w = wbase + wi;
            unsigned so0 = 0, so1 = 0, si0 = 0, si1 = 0;
            if (w < HWORDS) {
#pragma unroll
                for (int p = 0; p < HB; ++p) {
                    unsigned a  = phist[(size_t)(2 * p) * HWORDS + w];
                    unsigned bb = phist[(size_t)(2 * p + 1) * HWORDS + w];
                    so0 += a & 0xffffu; so1 += a >> 16;
                    si0 += bb & 0xffffu; si1 += bb >> 16;
                }
            }
#pragma unroll
            for (int hh = 0; hh < 2; ++hh) {
                int n = 2 * w + hh;
                unsigned so = hh ? so1 : so0, si = hh ? si1 : si0;
                int d = 0;
                if (n < Nn) {
                    d = (int)so;
                    float sn = 1.f / sqrtf(fmaxf((float)so, 1.f));
                    float dn = 1.f / sqrtf(fmaxf((float)si, 1.f));
                    srcn[n] = sn; pq[n] = sn * dn;
                    int g = gid[n];
                    atomicAdd(&lc[g], 1);
                    float zr[8];
#pragma unroll
                    for (int gg = 0; gg < 8; ++gg) zr[gg] = (gg == g) ? dn : 0.f;
                    *(float4*)(z + (size_t)n * 8)     = *(float4*)zr;
                    *(float4*)(z + (size_t)n * 8 + 4) = *(float4*)(zr + 4);
                }
                d4[wi * 2 + hh] = d;
            }
        }
        int s = (d4[0] + d4[1]) + (d4[2] + d4[3]);
        tsum[t] = s;
        __syncthreads();
        for (int off = 1; off < 256; off <<= 1) {
            int x = (t >= off) ? tsum[t - off] : 0;
            __syncthreads();
            tsum[t] += x;
            __syncthreads();
        }
        int run = tsum[t] - s;

        if (t == 0) atomicExch(&fs[b], (tsum[255] << 1) | 1);  // publish
        if (t < b) {                         // parallel lookback (b <= 48)
            int r;
            do { r = atomicAdd(&fs[t], 0); } while (!(r & 1));
            pre[t] = r >> 1;
        }
        __syncthreads();
        if (t == 0) {
            int base = 0;
            for (int p = 0; p < b; ++p) base += pre[p];
            sbase = base;
        }
        __syncthreads();

        int gpos = sbase + run;
#pragma unroll
        for (int i = 0; i < 4; ++i) {
            int n = b * 1024 + t * 4 + i;
            if (n < Nn) row_ptr[n] = gpos;
            gpos += d4[i];
        }
        if (b == NCHUNK - 1 && t == 255) row_ptr[Nn] = Ee;
        __syncthreads();
        if (t < Gg && lc[t] > 0) atomicAdd(&cnt[t], lc[t]);
    } else if (b < NCHUNK + W123_BLOCKS) {
        int j = (b - NCHUNK) * 2 + (t & 1);
        int k = t >> 1;
        float a = 0.f;
#pragma unroll 8
        for (int m = 0; m < 128; ++m) a += W12[k * 128 + m] * W3[m * 128 + j];
        W123[k * 128 + j] = a;
    } else {
        if (t < 128) {
            float a = 0.f;
#pragma unroll 8
            for (int k = 0; k < 128; ++k) a += e1[k] * W3[k * 128 + t];
            e1b[t] = a;
        }
    }
}

// ---------------- CSR fill via LDS cursors (no global atomics) -------------
// 16 blocks, one per src-hist chunk. LDS cursor[n] seeded with the prefix
// of earlier chunks' histograms (packed 16-bit add — halves independent,
// counts << 2^16). pos = row_ptr[src] + local fetch-add.
__global__ __launch_bounds__(1024) void fill_kernel(
    const int* __restrict__ src, const int* __restrict__ dst,
    const int* __restrict__ row_ptr, const unsigned int* __restrict__ phist,
    int* __restrict__ csr_dst)
{
    __shared__ unsigned int lcur[HWORDS];    // 100 KB
    int t = threadIdx.x, c = blockIdx.x;

    for (int w = t; w < HWORDS; w += 1024) {
        unsigned a = 0;
        for (int p = 0; p < c; ++p) a += phist[(size_t)(2 * p) * HWORDS + w];
        lcur[w] = a;
    }
    __syncthreads();

    int e0 = c * (Ee / HB);
    int e1 = e0 + (Ee / HB);
    for (int e = e0 + t; e < e1; e += 1024) {
        int s = src[e];
        int sh = (s & 1) << 4;
        unsigned old = atomicAdd(&lcur[s >> 1], 1u << sh);
        int lr = (old >> sh) & 0xffff;
        csr_dst[row_ptr[s] + lr] = dst[e];
    }
}

// ---------------- backward SpMM (N x 8), lockstep coalesced, 8-way ILP -----
__global__ __launch_bounds__(256) void bspmm_kernel(
    const float* __restrict__ uin, const int* __restrict__ row_ptr,
    const int* __restrict__ csr, const float* __restrict__ pqv,
    float* __restrict__ uout, const float* __restrict__ sn,
    float* __restrict__ pwout)
{
    int t = threadIdx.x;
    int g = t & 7;
    int m = blockIdx.x * 32 + (t >> 3);
    float acc = 0.f, snm = 0.f;
    if (m < Nn) {
        int beg = row_ptr[m], end = row_ptr[m + 1];
        int j = beg;
        float a0 = 0.f, a1 = 0.f, a2 = 0.f, a3 = 0.f;
        float a4 = 0.f, a5 = 0.f, a6 = 0.f, a7 = 0.f;
        for (; j + 7 < end; j += 8) {
            int i0 = csr[j],     i1 = csr[j + 1], i2 = csr[j + 2], i3 = csr[j + 3];
            int i4 = csr[j + 4], i5 = csr[j + 5], i6 = csr[j + 6], i7 = csr[j + 7];
            a0 += uin[(size_t)i0 * 8 + g]; a1 += uin[(size_t)i1 * 8 + g];
            a2 += uin[(size_t)i2 * 8 + g]; a3 += uin[(size_t)i3 * 8 + g];
            a4 += uin[(size_t)i4 * 8 + g]; a5 += uin[(size_t)i5 * 8 + g];
            a6 += uin[(size_t)i6 * 8 + g]; a7 += uin[(size_t)i7 * 8 + g];
        }
        for (; j + 3 < end; j += 4) {
            int i0 = csr[j], i1 = csr[j + 1], i2 = csr[j + 2], i3 = csr[j + 3];
            a0 += uin[(size_t)i0 * 8 + g]; a1 += uin[(size_t)i1 * 8 + g];
            a2 += uin[(size_t)i2 * 8 + g]; a3 += uin[(size_t)i3 * 8 + g];
        }
        for (; j < end; ++j) a0 += uin[(size_t)csr[j] * 8 + g];
        acc = ((a0 + a1) + (a2 + a3)) + ((a4 + a5) + (a6 + a7));
        uout[(size_t)m * 8 + g] = pqv[m] * acc;   // pre-scaled for next pass
        if (pwout) snm = sn[m];
    }
    if (pwout) {
        __shared__ float red[Gg];
        if (t < Gg) red[t] = 0.f;
        __syncthreads();
        float v = snm * acc;                 // raw-u dot sn
        v += __shfl_xor(v, 8, 64);
        v += __shfl_xor(v, 16, 64);
        v += __shfl_xor(v, 32, 64);
        if ((t & 63) < 8) atomicAdd(&red[t & 7], v);
        __syncthreads();
        if (t < Gg) atomicAdd(&pwout[t], red[t]);
    }
}

// ---------------- fused u3 + dense dot-pool, ownership-based (no atomics) --
__global__ __launch_bounds__(256) void dotpool_kernel(
    const float* __restrict__ x, const float* __restrict__ u2p,
    const float* __restrict__ sn,
    const int* __restrict__ row_ptr, const int* __restrict__ csr,
    float* __restrict__ partial)
{
    __shared__ float xs[DTILE][Dd];     // 32 KB
    __shared__ float f[DTILE][Gg];      // 2 KB
    int t = threadIdx.x;
    int n0 = blockIdx.x * DTILE;

    // stage x tile (coalesced): 2048 float4, 8 per thread
    {
        const float4* x4 = (const float4*)x;
        float4* xs4 = (float4*)xs;
#pragma unroll
        for (int k = 0; k < 8; ++k) {
            int idx = t + 256 * k;
            int i = idx >> 5;
            int n = n0 + i;
            xs4[idx] = (n < Nn) ? x4[(size_t)n * 32 + (idx & 31)]
                                : make_float4(0.f, 0.f, 0.f, 0.f);
        }
    }

    // phase 1: 4 lanes/node (g-pair), lockstep coalesced float2, 4-way ILP
    {
        int i = t >> 2, sub = t & 3;
        int n = n0 + i;
        float ax = 0.f, ay = 0.f, s = 0.f;
        if (n < Nn) {
            s = sn[n];
            int beg = row_ptr[n], end = row_ptr[n + 1];
            int j = beg;
            float bx = 0.f, by = 0.f, cx = 0.f, cy = 0.f, dx = 0.f, dy = 0.f;
            for (; j + 3 < end; j += 4) {
                int i0 = csr[j], i1 = csr[j + 1], i2 = csr[j + 2], i3 = csr[j + 3];
                float2 u0 = *(const float2*)(u2p + (size_t)i0 * 8 + sub * 2);
                float2 u1 = *(const float2*)(u2p + (size_t)i1 * 8 + sub * 2);
                float2 u2 = *(const float2*)(u2p + (size_t)i2 * 8 + sub * 2);
                float2 u3 = *(const float2*)(u2p + (size_t)i3 * 8 + sub * 2);
                ax += u0.x; ay += u0.y; bx += u1.x; by += u1.y;
                cx += u2.x; cy += u2.y; dx += u3.x; dy += u3.y;
            }
            for (; j < end; ++j) {
                float2 u = *(const float2*)(u2p + (size_t)csr[j] * 8 + sub * 2);
                ax += u.x; ay += u.y;
            }
            ax += bx + cx + dx; ay += by + cy + dy;
        }
        f[i][sub * 2 + 0] = s * ax;
        f[i][sub * 2 + 1] = s * ay;
    }
    __syncthreads();

    // phase 2: ownership — thread (g = t>>5, c = t&31)
    {
        int g = t >> 5, c = t & 31;
        float4 acc = {0.f, 0.f, 0.f, 0.f};
#pragma unroll 8
        for (int i = 0; i < DTILE; ++i) {
            float fv = f[i][g];
            float4 xv = *(const float4*)&xs[i][c * 4];
            acc.x += fv * xv.x; acc.y += fv * xv.y;
            acc.z += fv * xv.z; acc.w += fv * xv.w;
        }
        *(float4*)(partial + (size_t)blockIdx.x * 1024 + g * 128 + c * 4) = acc;
    }
}

// ---------------- reduce stage A: 782 partials -> 128 partials -------------
__global__ __launch_bounds__(256) void dotreduceA_kernel(
    const float* __restrict__ partial, float* __restrict__ partial2)
{
    int b = blockIdx.x, t = threadIdx.x;
    int p0 = b * RA_CHUNK;
    int p1 = p0 + RA_CHUNK; if (p1 > DPBLK) p1 = DPBLK;
    float a0 = 0.f, a1 = 0.f, a2 = 0.f, a3 = 0.f;
    for (int p = p0; p < p1; ++p) {
        const float* pp = partial + (size_t)p * 1024;
        a0 += pp[t];
        a1 += pp[t + 256];
        a2 += pp[t + 512];
        a3 += pp[t + 768];
    }
    float* o = partial2 + (size_t)b * 1024;
    o[t] = a0; o[t + 256] = a1; o[t + 512] = a2; o[t + 768] = a3;
}

// ---------------- merged reduceB + x0 + fc1: 32 blocks ---------------------
__global__ __launch_bounds__(256) void redfc1_kernel(
    const float* __restrict__ partial2, const float* __restrict__ pw1r,
    const float* __restrict__ pw2r, const int* __restrict__ cnt,
    const float* __restrict__ W123, const float* __restrict__ e1b,
    const float* __restrict__ e2, const float* __restrict__ b3,
    const float* __restrict__ Wc1, const float* __restrict__ bc1,
    float* __restrict__ x1g)
{
    __shared__ float prow[128];
    __shared__ float x0row[128];
    __shared__ float psum[256];
    int b = blockIdx.x, t = threadIdx.x;
    int g = b >> 2, q = b & 3;

    // stage 1: pooled row g (sum 128 partial2 rows, 2-way k-split)
    {
        int k = t & 127, h = t >> 7;
        float a0 = 0.f, a1 = 0.f;
        int p0 = h * 64;
        for (int p = p0; p < p0 + 64; p += 2) {
            a0 += partial2[(size_t)p * 1024 + g * 128 + k];
            a1 += partial2[(size_t)(p + 1) * 1024 + g * 128 + k];
        }
        psum[t] = a0 + a1;
        __syncthreads();
        if (t < 128) prow[t] = psum[t] + psum[t + 128];
        __syncthreads();
    }
    // stage 2: x0 row g
    {
        int c = t & 127, h = t >> 7;
        float a = 0.f;
        int k0 = h * 64;
#pragma unroll 8
        for (int k = k0; k < k0 + 64; ++k) a += prow[k] * W123[k * 128 + c];
        psum[t] = a;
        __syncthreads();
        if (t < 128) {
            float inv = 1.f / fmaxf((float)cnt[g], 1.f);
            x0row[t] = (psum[t] + psum[t + 128]) * inv
                     + (pw2r[g] * inv) * e1b[t] + (pw1r[g] * inv) * e2[t] + b3[t];
        }
        __syncthreads();
    }
    // stage 3: fc1 quarter q
    {
        int m = q * 128 + (t & 127), h = t >> 7;
        float a = 0.f;
        int k0 = h * 64;
#pragma unroll 8
        for (int k = k0; k < k0 + 64; ++k)
            a += x0row[k] * Wc1[(size_t)k * 512 + m];
        psum[t] = a;
        __syncthreads();
        if (t < 128) {
            int m2 = q * 128 + t;
            float v = psum[t] + psum[t + 128] + bc1[m2];
            x1g[g * 512 + m2] = v > 0.f ? v : 0.01f * v;
        }
    }
}

// ---------------- head: fc2 (512->256), 32 blocks --------------------------
__global__ __launch_bounds__(256) void fc2_kernel(
    const float* __restrict__ x1g, const float* __restrict__ Wc2,
    const float* __restrict__ bc2, float* __restrict__ x2g)
{
    __shared__ float xs[Gg * 512];
    __shared__ float par[256];
    int t = threadIdx.x;
    for (int i = t; i < Gg * 512; i += 256) xs[i] = x1g[i];
    __syncthreads();
    int q = t >> 6, rem = t & 63;
    int g = rem >> 3, m = blockIdx.x * 8 + (rem & 7);
    int k0 = q * 128;
    float a = 0.f;
#pragma unroll 16
    for (int k = 0; k < 128; ++k) a += xs[g * 512 + k0 + k] * Wc2[(size_t)(k0 + k) * 256 + m];
    par[t] = a;
    __syncthreads();
    if (t < 64) {
        float v = par[t] + par[t + 64] + par[t + 128] + par[t + 192] + bc2[m];
        x2g[g * 256 + m] = v > 0.f ? v : 0.01f * v;
    }
}

// ---------------- head: fc3 (256->10), 1 block -----------------------------
__global__ __launch_bounds__(640) void fc3_kernel(
    const float* __restrict__ x2g, const float* __restrict__ Wc3,
    const float* __restrict__ bc3, float* __restrict__ out)
{
    __shared__ float xs[Gg * 256];
    int t = threadIdx.x;
    for (int i = t; i < Gg * 256; i += 640) xs[i] = x2g[i];
    __syncthreads();
    int w = t >> 6, lane = t & 63;
    if (w < 10) {
        float acc[Gg];
#pragma unroll
        for (int g = 0; g < Gg; ++g) acc[g] = 0.f;
#pragma unroll
        for (int kk = 0; kk < 4; ++kk) {
            int k = lane + kk * 64;
            float wv = Wc3[(size_t)k * 10 + w];
#pragma unroll
            for (int g = 0; g < Gg; ++g) acc[g] += xs[g * 256 + k] * wv;
        }
#pragma unroll
        for (int g = 0; g < Gg; ++g) {
            float v = acc[g];
            for (int off = 32; off; off >>= 1) v += __shfl_down(v, off, 64);
            if (lane == 0) {
                v += bc3[w];
                out[g * 10 + w] = v > 0.f ? v : 0.01f * v;
            }
        }
    }
}

extern "C" void kernel_launch(void* const* d_in, const int* in_sizes, int n_in,
                              void* d_out, int out_size, void* d_ws, size_t ws_size,
                              hipStream_t stream)
{
    const float* inputs = (const float*)d_in[0];
    const int*   src    = (const int*)d_in[1];
    const int*   dst    = (const int*)d_in[2];
    const int*   gid    = (const int*)d_in[3];
    const float* W1  = (const float*)d_in[4];
    const float* b1  = (const float*)d_in[5];
    const float* W2  = (const float*)d_in[6];
    const float* b2  = (const float*)d_in[7];
    const float* W3  = (const float*)d_in[8];
    const float* b3  = (const float*)d_in[9];
    const float* Wc1 = (const float*)d_in[10];
    const float* bc1 = (const float*)d_in[11];
    const float* Wc2 = (const float*)d_in[12];
    const float* bc2 = (const float*)d_in[13];
    const float* Wc3 = (const float*)d_in[14];
    const float* bc3 = (const float*)d_in[15];

    // ---- workspace layout ----
    int*   wi      = (int*)d_ws;
    int*   row_ptr = wi;                       // NP (uses N+1)
    int*   csr_dst = row_ptr + NP;             // Ee
    float* wf      = (float*)(csr_dst + Ee);
    float* srcn    = wf;                       // NP
    float* pq      = srcn + NP;                // NP
    float* z       = pq + NP;                  // NP*8
    float* u1      = z + (size_t)NP * 8;       // NP*8 (pq-prescaled)
    float* u2      = u1 + (size_t)NP * 8;      // NP*8 (pq-prescaled)
    float* partial = u2 + (size_t)NP * 8;      // DPBLK*1024
    float* partial2= partial + (size_t)DPBLK * 1024;  // RA_BLOCKS*1024
    float* pw1     = partial2 + (size_t)RA_BLOCKS * 1024;  // 8
    float* pw2     = pw1 + Gg;                 // 8
    int*   cnt     = (int*)(pw2 + Gg);         // 8
    int*   fs      = cnt + Gg;                 // 64 (lookback flags)
    float* W12v    = (float*)(fs + 64);        // 128*128
    float* W123v   = W12v + 128 * 128;         // 128*128
    float* e1v     = W123v + 128 * 128;        // 128
    float* e1bv    = e1v + 128;                // 128
    float* e2v     = e1bv + 128;               // 128
    float* x1g     = e2v + 128;                // 4096
    float* x2g     = x1g + 4096;               // 2048
    unsigned int* phist = (unsigned int*)(x2g + 2048);  // 32*HWORDS

    // 1. histograms + W12/e1/e2 + zero pw1/pw2/cnt/flags
    hist_kernel<<<HIST_BLOCKS + W12_BLOCKS + 1, 1024, 0, stream>>>(
        src, dst, phist, W1, W2, W3, b1, b2, W12v, e1v, e2v, (int*)pw1);
    // 2. fused: partial-reduce -> norms/z/cnt + lookback scan -> row_ptr
    scan_fused<<<NCHUNK + W123_BLOCKS + 1, 256, 0, stream>>>(
        phist, gid, srcn, pq, z, cnt, row_ptr, fs,
        W12v, W3, e1v, W123v, e1bv);
    // 3. CSR fill via LDS cursors (16 blocks, no global atomics)
    fill_kernel<<<HB, 1024, 0, stream>>>(src, dst, row_ptr, phist, csr_dst);

    // 4-5. backward chain (pq applied at producer; u3 folded into dotpool)
    int bblocks = (Nn + 31) / 32;
    bspmm_kernel<<<bblocks, 256, 0, stream>>>(z, row_ptr, csr_dst, pq,
                                              u1, srcn, pw1);
    bspmm_kernel<<<bblocks, 256, 0, stream>>>(u1, row_ptr, csr_dst, pq,
                                              u2, srcn, pw2);

    // 6. fused u3 + dot-pool (64-node tiles, 782 blocks, atomic-free)
    dotpool_kernel<<<DPBLK, 256, 0, stream>>>(inputs, u2, srcn,
                                              row_ptr, csr_dst, partial);
    // 7. tree reduce stage A (782 -> 128)
    dotreduceA_kernel<<<RA_BLOCKS, 256, 0, stream>>>(partial, partial2);
    // 8. merged reduceB + x0 + fc1
    redfc1_kernel<<<32, 256, 0, stream>>>(partial2, pw1, pw2, cnt,
                                          W123v, e1bv, e2v, b3, Wc1, bc1, x1g);
    // 9-10. fc2, fc3
    fc2_kernel<<<32, 256, 0, stream>>>(x1g, Wc2, bc2, x2g);
    fc3_kernel<<<1, 640, 0, stream>>>(x2g, Wc3, bc3, (float*)d_out);
}

// Round 21
// 158.823 us; speedup vs baseline: 1.5780x; 1.5780x over previous
//
#include <hip/hip_runtime.h>

#define Nn 50000
#define Ee 600000
#define Gg 8
#define Dd 128
#define NP 50048
#define NCHUNK 49           // scan blocks (1024 nodes each)

#define HWORDS 25024        // ceil(N/2); 2x16-bit counters per word
#define HB 16
#define HIST_BLOCKS (2 * HB)          // 32
#define W12_BLOCKS 16
#define W123_BLOCKS 64
#define DTILE 64
#define DPBLK ((Nn + DTILE - 1) / DTILE)   // 782
#define RA_BLOCKS 128
#define RA_CHUNK ((DPBLK + RA_BLOCKS - 1) / RA_BLOCKS)  // 7

// ---------------- hist + piggyback W12/e1/e2 + zero accumulators/flags ----
__global__ __launch_bounds__(1024) void hist_kernel(
    const int* __restrict__ src, const int* __restrict__ dst,
    unsigned int* __restrict__ phist,
    const float* __restrict__ W1, const float* __restrict__ W2,
    const float* __restrict__ W3, const float* __restrict__ b1,
    const float* __restrict__ b2,
    float* __restrict__ W12, float* __restrict__ e1, float* __restrict__ e2,
    int* __restrict__ accz)   // pw1(8),pw2(8),cnt(8),fs(64) -> 88 words
{
    __shared__ unsigned int h[HWORDS];
    int t = threadIdx.x;
    int b = blockIdx.x;

    if (b < HIST_BLOCKS) {
        for (int i = t; i < HWORDS; i += 1024) h[i] = 0u;
        __syncthreads();
        int part = b >> 1;
        const int* arr = (b & 1) ? dst : src;
        int e0 = part * (Ee / HB);
        int eN = e0 + (Ee / HB);
        for (int e = e0 + t; e < eN; e += 1024) {
            int n = arr[e];
            atomicAdd(&h[n >> 1], 1u << ((n & 1) << 4));
        }
        __syncthreads();
        unsigned int* out = phist + (size_t)b * HWORDS;
        for (int i = t; i < HWORDS; i += 1024) out[i] = h[i];
    } else if (b < HIST_BLOCKS + W12_BLOCKS) {
        int j = (b - HIST_BLOCKS) * 8 + (t & 7);
        int k = t >> 3;
        float a = 0.f;
#pragma unroll 8
        for (int m = 0; m < 128; ++m) a += W1[k * 128 + m] * W2[m * 128 + j];
        W12[k * 128 + j] = a;
    } else {
        if (t < 128) {
            float a = 0.f;
#pragma unroll 8
            for (int k = 0; k < 128; ++k) a += b1[k] * W2[k * 128 + t];
            e1[t] = a;
        } else if (t < 256) {
            int c = t - 128;
            float a = 0.f;
#pragma unroll 8
            for (int k = 0; k < 128; ++k) a += b2[k] * W3[k * 128 + c];
            e2[c] = a;
        } else if (t < 256 + 88) {
            accz[t - 256] = 0;      // zero pw1, pw2, cnt, lookback flags
        }
    }
}

// ---------------- fused: partial-reduce + norms + z + lookback scan --------
__global__ __launch_bounds__(256) void scan_fused(
    const unsigned int* __restrict__ phist, const int* __restrict__ gid,
    float* __restrict__ srcn, float* __restrict__ pq, float* __restrict__ z,
    int* __restrict__ cnt, int* __restrict__ row_ptr, int* __restrict__ cursor,
    int* __restrict__ fs,
    const float* __restrict__ W12, const float* __restrict__ W3,
    const float* __restrict__ e1,
    float* __restrict__ W123, float* __restrict__ e1b)
{
    int b = blockIdx.x, t = threadIdx.x;
    if (b < NCHUNK) {
        __shared__ int tsum[256];
        __shared__ int lc[Gg];
        __shared__ int pre[64];
        __shared__ int sbase;
        if (t < Gg) lc[t] = 0;
        __syncthreads();

        int d4[4];
        int wbase = b * 512 + t * 2;
#pragma unroll
        for (int wi = 0; wi < 2; ++wi) {
            int w = wbase + wi;
            unsigned so0 = 0, so1 = 0, si0 = 0, si1 = 0;
            if (w < HWORDS) {
#pragma unroll
                for (int p = 0; p < HB; ++p) {
                    unsigned a  = phist[(size_t)(2 * p) * HWORDS + w];
                    unsigned bb = phist[(size_t)(2 * p + 1) * HWORDS + w];
                    so0 += a & 0xffffu; so1 += a >> 16;
                    si0 += bb & 0xffffu; si1 += bb >> 16;
                }
            }
#pragma unroll
            for (int hh = 0; hh < 2; ++hh) {
                int n = 2 * w + hh;
                unsigned so = hh ? so1 : so0, si = hh ? si1 : si0;
                int d = 0;
                if (n < Nn) {
                    d = (int)so;
                    float sn = 1.f / sqrtf(fmaxf((float)so, 1.f));
                    float dn = 1.f / sqrtf(fmaxf((float)si, 1.f));
                    srcn[n] = sn; pq[n] = sn * dn;
                    int g = gid[n];
                    atomicAdd(&lc[g], 1);
                    float zr[8];
#pragma unroll
                    for (int gg = 0; gg < 8; ++gg) zr[gg] = (gg == g) ? dn : 0.f;
                    *(float4*)(z + (size_t)n * 8)     = *(float4*)zr;
                    *(float4*)(z + (size_t)n * 8 + 4) = *(float4*)(zr + 4);
                }
                d4[wi * 2 + hh] = d;
            }
        }
        int s = (d4[0] + d4[1]) + (d4[2] + d4[3]);
        tsum[t] = s;
        __syncthreads();
        for (int off = 1; off < 256; off <<= 1) {
            int x = (t >= off) ? tsum[t - off] : 0;
            __syncthreads();
            tsum[t] += x;
            __syncthreads();
        }
        int run = tsum[t] - s;

        if (t == 0) atomicExch(&fs[b], (tsum[255] << 1) | 1);  // publish
        if (t < b) {                         // parallel lookback (b <= 48)
            int r;
            do { r = atomicAdd(&fs[t], 0); } while (!(r & 1));
            pre[t] = r >> 1;
        }
        __syncthreads();
        if (t == 0) {
            int base = 0;
            for (int p = 0; p < b; ++p) base += pre[p];
            sbase = base;
        }
        __syncthreads();

        int gpos = sbase + run;
#pragma unroll
        for (int i = 0; i < 4; ++i) {
            int n = b * 1024 + t * 4 + i;
            if (n < Nn) { row_ptr[n] = gpos; cursor[n] = gpos; }
            gpos += d4[i];
        }
        if (b == NCHUNK - 1 && t == 255) row_ptr[Nn] = Ee;
        __syncthreads();
        if (t < Gg && lc[t] > 0) atomicAdd(&cnt[t], lc[t]);
    } else if (b < NCHUNK + W123_BLOCKS) {
        int j = (b - NCHUNK) * 2 + (t & 1);
        int k = t >> 1;
        float a = 0.f;
#pragma unroll 8
        for (int m = 0; m < 128; ++m) a += W12[k * 128 + m] * W3[m * 128 + j];
        W123[k * 128 + j] = a;
    } else {
        if (t < 128) {
            float a = 0.f;
#pragma unroll 8
            for (int k = 0; k < 128; ++k) a += e1[k] * W3[k * 128 + t];
            e1b[t] = a;
        }
    }
}

// ---------------- CSR-by-src fill (1 edge/thread, global cursor) -----------
__global__ __launch_bounds__(256) void fill_kernel(
    const int* __restrict__ src, const int* __restrict__ dst,
    int* __restrict__ cursor, int* __restrict__ csr_dst)
{
    int e = blockIdx.x * 256 + threadIdx.x;
    if (e >= Ee) return;
    int pos = atomicAdd(&cursor[src[e]], 1);
    csr_dst[pos] = dst[e];
}

// ---------------- backward SpMM (N x 8), lockstep coalesced, 8-way ILP -----
__global__ __launch_bounds__(256) void bspmm_kernel(
    const float* __restrict__ uin, const int* __restrict__ row_ptr,
    const int* __restrict__ csr, const float* __restrict__ pqv,
    float* __restrict__ uout, const float* __restrict__ sn,
    float* __restrict__ pwout)
{
    int t = threadIdx.x;
    int g = t & 7;
    int m = blockIdx.x * 32 + (t >> 3);
    float acc = 0.f, snm = 0.f;
    if (m < Nn) {
        int beg = row_ptr[m], end = row_ptr[m + 1];
        int j = beg;
        float a0 = 0.f, a1 = 0.f, a2 = 0.f, a3 = 0.f;
        float a4 = 0.f, a5 = 0.f, a6 = 0.f, a7 = 0.f;
        for (; j + 7 < end; j += 8) {
            int i0 = csr[j],     i1 = csr[j + 1], i2 = csr[j + 2], i3 = csr[j + 3];
            int i4 = csr[j + 4], i5 = csr[j + 5], i6 = csr[j + 6], i7 = csr[j + 7];
            a0 += uin[(size_t)i0 * 8 + g]; a1 += uin[(size_t)i1 * 8 + g];
            a2 += uin[(size_t)i2 * 8 + g]; a3 += uin[(size_t)i3 * 8 + g];
            a4 += uin[(size_t)i4 * 8 + g]; a5 += uin[(size_t)i5 * 8 + g];
            a6 += uin[(size_t)i6 * 8 + g]; a7 += uin[(size_t)i7 * 8 + g];
        }
        for (; j + 3 < end; j += 4) {
            int i0 = csr[j], i1 = csr[j + 1], i2 = csr[j + 2], i3 = csr[j + 3];
            a0 += uin[(size_t)i0 * 8 + g]; a1 += uin[(size_t)i1 * 8 + g];
            a2 += uin[(size_t)i2 * 8 + g]; a3 += uin[(size_t)i3 * 8 + g];
        }
        for (; j < end; ++j) a0 += uin[(size_t)csr[j] * 8 + g];
        acc = ((a0 + a1) + (a2 + a3)) + ((a4 + a5) + (a6 + a7));
        uout[(size_t)m * 8 + g] = pqv[m] * acc;   // pre-scaled for next pass
        if (pwout) snm = sn[m];
    }
    if (pwout) {
        __shared__ float red[Gg];
        if (t < Gg) red[t] = 0.f;
        __syncthreads();
        float v = snm * acc;                 // raw-u dot sn
        v += __shfl_xor(v, 8, 64);
        v += __shfl_xor(v, 16, 64);
        v += __shfl_xor(v, 32, 64);
        if ((t & 63) < 8) atomicAdd(&red[t & 7], v);
        __syncthreads();
        if (t < Gg) atomicAdd(&pwout[t], red[t]);
    }
}

// ---------------- fused u3 + dense dot-pool, ownership-based (no atomics) --
__global__ __launch_bounds__(256) void dotpool_kernel(
    const float* __restrict__ x, const float* __restrict__ u2p,
    const float* __restrict__ sn,
    const int* __restrict__ row_ptr, const int* __restrict__ csr,
    float* __restrict__ partial)
{
    __shared__ float xs[DTILE][Dd];     // 32 KB
    __shared__ float f[DTILE][Gg];      // 2 KB
    int t = threadIdx.x;
    int n0 = blockIdx.x * DTILE;

    // stage x tile (coalesced): 2048 float4, 8 per thread
    {
        const float4* x4 = (const float4*)x;
        float4* xs4 = (float4*)xs;
#pragma unroll
        for (int k = 0; k < 8; ++k) {
            int idx = t + 256 * k;
            int i = idx >> 5;
            int n = n0 + i;
            xs4[idx] = (n < Nn) ? x4[(size_t)n * 32 + (idx & 31)]
                                : make_float4(0.f, 0.f, 0.f, 0.f);
        }
    }

    // phase 1: 4 lanes/node (g-pair), lockstep coalesced float2, 4-way ILP
    {
        int i = t >> 2, sub = t & 3;
        int n = n0 + i;
        float ax = 0.f, ay = 0.f, s = 0.f;
        if (n < Nn) {
            s = sn[n];
            int beg = row_ptr[n], end = row_ptr[n + 1];
            int j = beg;
            float bx = 0.f, by = 0.f, cx = 0.f, cy = 0.f, dx = 0.f, dy = 0.f;
            for (; j + 3 < end; j += 4) {
                int i0 = csr[j], i1 = csr[j + 1], i2 = csr[j + 2], i3 = csr[j + 3];
                float2 u0 = *(const float2*)(u2p + (size_t)i0 * 8 + sub * 2);
                float2 u1 = *(const float2*)(u2p + (size_t)i1 * 8 + sub * 2);
                float2 u2 = *(const float2*)(u2p + (size_t)i2 * 8 + sub * 2);
                float2 u3 = *(const float2*)(u2p + (size_t)i3 * 8 + sub * 2);
                ax += u0.x; ay += u0.y; bx += u1.x; by += u1.y;
                cx += u2.x; cy += u2.y; dx += u3.x; dy += u3.y;
            }
            for (; j < end; ++j) {
                float2 u = *(const float2*)(u2p + (size_t)csr[j] * 8 + sub * 2);
                ax += u.x; ay += u.y;
            }
            ax += bx + cx + dx; ay += by + cy + dy;
        }
        f[i][sub * 2 + 0] = s * ax;
        f[i][sub * 2 + 1] = s * ay;
    }
    __syncthreads();

    // phase 2: ownership — thread (g = t>>5, c = t&31)
    {
        int g = t >> 5, c = t & 31;
        float4 acc = {0.f, 0.f, 0.f, 0.f};
#pragma unroll 8
        for (int i = 0; i < DTILE; ++i) {
            float fv = f[i][g];
            float4 xv = *(const float4*)&xs[i][c * 4];
            acc.x += fv * xv.x; acc.y += fv * xv.y;
            acc.z += fv * xv.z; acc.w += fv * xv.w;
        }
        *(float4*)(partial + (size_t)blockIdx.x * 1024 + g * 128 + c * 4) = acc;
    }
}

// ---------------- reduce stage A: 782 partials -> 128 partials -------------
__global__ __launch_bounds__(256) void dotreduceA_kernel(
    const float* __restrict__ partial, float* __restrict__ partial2)
{
    int b = blockIdx.x, t = threadIdx.x;
    int p0 = b * RA_CHUNK;
    int p1 = p0 + RA_CHUNK; if (p1 > DPBLK) p1 = DPBLK;
    float a0 = 0.f, a1 = 0.f, a2 = 0.f, a3 = 0.f;
    for (int p = p0; p < p1; ++p) {
        const float* pp = partial + (size_t)p * 1024;
        a0 += pp[t];
        a1 += pp[t + 256];
        a2 += pp[t + 512];
        a3 += pp[t + 768];
    }
    float* o = partial2 + (size_t)b * 1024;
    o[t] = a0; o[t + 256] = a1; o[t + 512] = a2; o[t + 768] = a3;
}

// ---------------- merged reduceB + x0 + fc1: 32 blocks ---------------------
__global__ __launch_bounds__(256) void redfc1_kernel(
    const float* __restrict__ partial2, const float* __restrict__ pw1r,
    const float* __restrict__ pw2r, const int* __restrict__ cnt,
    const float* __restrict__ W123, const float* __restrict__ e1b,
    const float* __restrict__ e2, const float* __restrict__ b3,
    const float* __restrict__ Wc1, const float* __restrict__ bc1,
    float* __restrict__ x1g)
{
    __shared__ float prow[128];
    __shared__ float x0row[128];
    __shared__ float psum[256];
    int b = blockIdx.x, t = threadIdx.x;
    int g = b >> 2, q = b & 3;

    // stage 1: pooled row g (sum 128 partial2 rows, 2-way k-split)
    {
        int k = t & 127, h = t >> 7;
        float a0 = 0.f, a1 = 0.f;
        int p0 = h * 64;
        for (int p = p0; p < p0 + 64; p += 2) {
            a0 += partial2[(size_t)p * 1024 + g * 128 + k];
            a1 += partial2[(size_t)(p + 1) * 1024 + g * 128 + k];
        }
        psum[t] = a0 + a1;
        __syncthreads();
        if (t < 128) prow[t] = psum[t] + psum[t + 128];
        __syncthreads();
    }
    // stage 2: x0 row g
    {
        int c = t & 127, h = t >> 7;
        float a = 0.f;
        int k0 = h * 64;
#pragma unroll 8
        for (int k = k0; k < k0 + 64; ++k) a += prow[k] * W123[k * 128 + c];
        psum[t] = a;
        __syncthreads();
        if (t < 128) {
            float inv = 1.f / fmaxf((float)cnt[g], 1.f);
            x0row[t] = (psum[t] + psum[t + 128]) * inv
                     + (pw2r[g] * inv) * e1b[t] + (pw1r[g] * inv) * e2[t] + b3[t];
        }
        __syncthreads();
    }
    // stage 3: fc1 quarter q
    {
        int m = q * 128 + (t & 127), h = t >> 7;
        float a = 0.f;
        int k0 = h * 64;
#pragma unroll 8
        for (int k = k0; k < k0 + 64; ++k)
            a += x0row[k] * Wc1[(size_t)k * 512 + m];
        psum[t] = a;
        __syncthreads();
        if (t < 128) {
            int m2 = q * 128 + t;
            float v = psum[t] + psum[t + 128] + bc1[m2];
            x1g[g * 512 + m2] = v > 0.f ? v : 0.01f * v;
        }
    }
}

// ---------------- head: fc2 (512->256), 32 blocks --------------------------
__global__ __launch_bounds__(256) void fc2_kernel(
    const float* __restrict__ x1g, const float* __restrict__ Wc2,
    const float* __restrict__ bc2, float* __restrict__ x2g)
{
    __shared__ float xs[Gg * 512];
    __shared__ float par[256];
    int t = threadIdx.x;
    for (int i = t; i < Gg * 512; i += 256) xs[i] = x1g[i];
    __syncthreads();
    int q = t >> 6, rem = t & 63;
    int g = rem >> 3, m = blockIdx.x * 8 + (rem & 7);
    int k0 = q * 128;
    float a = 0.f;
#pragma unroll 16
    for (int k = 0; k < 128; ++k) a += xs[g * 512 + k0 + k] * Wc2[(size_t)(k0 + k) * 256 + m];
    par[t] = a;
    __syncthreads();
    if (t < 64) {
        float v = par[t] + par[t + 64] + par[t + 128] + par[t + 192] + bc2[m];
        x2g[g * 256 + m] = v > 0.f ? v : 0.01f * v;
    }
}

// ---------------- head: fc3 (256->10), 1 block -----------------------------
__global__ __launch_bounds__(640) void fc3_kernel(
    const float* __restrict__ x2g, const float* __restrict__ Wc3,
    const float* __restrict__ bc3, float* __restrict__ out)
{
    __shared__ float xs[Gg * 256];
    int t = threadIdx.x;
    for (int i = t; i < Gg * 256; i += 640) xs[i] = x2g[i];
    __syncthreads();
    int w = t >> 6, lane = t & 63;
    if (w < 10) {
        float acc[Gg];
#pragma unroll
        for (int g = 0; g < Gg; ++g) acc[g] = 0.f;
#pragma unroll
        for (int kk = 0; kk < 4; ++kk) {
            int k = lane + kk * 64;
            float wv = Wc3[(size_t)k * 10 + w];
#pragma unroll
            for (int g = 0; g < Gg; ++g) acc[g] += xs[g * 256 + k] * wv;
        }
#pragma unroll
        for (int g = 0; g < Gg; ++g) {
            float v = acc[g];
            for (int off = 32; off; off >>= 1) v += __shfl_down(v, off, 64);
            if (lane == 0) {
                v += bc3[w];
                out[g * 10 + w] = v > 0.f ? v : 0.01f * v;
            }
        }
    }
}

extern "C" void kernel_launch(void* const* d_in, const int* in_sizes, int n_in,
                              void* d_out, int out_size, void* d_ws, size_t ws_size,
                              hipStream_t stream)
{
    const float* inputs = (const float*)d_in[0];
    const int*   src    = (const int*)d_in[1];
    const int*   dst    = (const int*)d_in[2];
    const int*   gid    = (const int*)d_in[3];
    const float* W1  = (const float*)d_in[4];
    const float* b1  = (const float*)d_in[5];
    const float* W2  = (const float*)d_in[6];
    const float* b2  = (const float*)d_in[7];
    const float* W3  = (const float*)d_in[8];
    const float* b3  = (const float*)d_in[9];
    const float* Wc1 = (const float*)d_in[10];
    const float* bc1 = (const float*)d_in[11];
    const float* Wc2 = (const float*)d_in[12];
    const float* bc2 = (const float*)d_in[13];
    const float* Wc3 = (const float*)d_in[14];
    const float* bc3 = (const float*)d_in[15];

    // ---- workspace layout ----
    int*   wi      = (int*)d_ws;
    int*   row_ptr = wi;                       // NP (uses N+1)
    int*   cursor  = row_ptr + NP;             // NP
    int*   csr_dst = cursor + NP;              // Ee
    float* wf      = (float*)(csr_dst + Ee);
    float* srcn    = wf;                       // NP
    float* pq      = srcn + NP;                // NP
    float* z       = pq + NP;                  // NP*8
    float* u1      = z + (size_t)NP * 8;       // NP*8 (pq-prescaled)
    float* u2      = u1 + (size_t)NP * 8;      // NP*8 (pq-prescaled)
    float* partial = u2 + (size_t)NP * 8;      // DPBLK*1024
    float* partial2= partial + (size_t)DPBLK * 1024;  // RA_BLOCKS*1024
    float* pw1     = partial2 + (size_t)RA_BLOCKS * 1024;  // 8
    float* pw2     = pw1 + Gg;                 // 8
    int*   cnt     = (int*)(pw2 + Gg);         // 8
    int*   fs      = cnt + Gg;                 // 64 (lookback flags)
    float* W12v    = (float*)(fs + 64);        // 128*128
    float* W123v   = W12v + 128 * 128;         // 128*128
    float* e1v     = W123v + 128 * 128;        // 128
    float* e1bv    = e1v + 128;                // 128
    float* e2v     = e1bv + 128;               // 128
    float* x1g     = e2v + 128;                // 4096
    float* x2g     = x1g + 4096;               // 2048
    unsigned int* phist = (unsigned int*)(x2g + 2048);  // 32*HWORDS

    // 1. histograms + W12/e1/e2 + zero pw1/pw2/cnt/flags
    hist_kernel<<<HIST_BLOCKS + W12_BLOCKS + 1, 1024, 0, stream>>>(
        src, dst, phist, W1, W2, W3, b1, b2, W12v, e1v, e2v, (int*)pw1);
    // 2. fused: partial-reduce -> norms/z/cnt + lookback scan -> row_ptr/cursor
    scan_fused<<<NCHUNK + W123_BLOCKS + 1, 256, 0, stream>>>(
        phist, gid, srcn, pq, z, cnt, row_ptr, cursor, fs,
        W12v, W3, e1v, W123v, e1bv);
    // 3. CSR fill (1 edge/thread, global cursor atomics — measured best)
    fill_kernel<<<(Ee + 255) / 256, 256, 0, stream>>>(src, dst, cursor, csr_dst);

    // 4-5. backward chain (pq applied at producer; u3 folded into dotpool)
    int bblocks = (Nn + 31) / 32;
    bspmm_kernel<<<bblocks, 256, 0, stream>>>(z, row_ptr, csr_dst, pq,
                                              u1, srcn, pw1);
    bspmm_kernel<<<bblocks, 256, 0, stream>>>(u1, row_ptr, csr_dst, pq,
                                              u2, srcn, pw2);

    // 6. fused u3 + dot-pool (64-node tiles, 782 blocks, atomic-free)
    dotpool_kernel<<<DPBLK, 256, 0, stream>>>(inputs, u2, srcn,
                                              row_ptr, csr_dst, partial);
    // 7. tree reduce stage A (782 -> 128)
    dotreduceA_kernel<<<RA_BLOCKS, 256, 0, stream>>>(partial, partial2);
    // 8. merged reduceB + x0 + fc1
    redfc1_kernel<<<32, 256, 0, stream>>>(partial2, pw1, pw2, cnt,
                                          W123v, e1bv, e2v, b3, Wc1, bc1, x1g);
    // 9-10. fc2, fc3
    fc2_kernel<<<32, 256, 0, stream>>>(x1g, Wc2, bc2, x2g);
    fc3_kernel<<<1, 640, 0, stream>>>(x2g, Wc3, bc3, (float*)d_out);
}